// Round 1
// baseline (1335.022 us; speedup 1.0000x reference)
//
#include <hip/hip_runtime.h>

// Segmented sum: values (1048576, 256) fp32, segment_ids sorted (1048576,) int32,
// out (512, 256) fp32. Memory-bound: 1.074 GB read, ~170 us roofline at 6.3 TB/s.

#define TOTAL_POINTS 1048576
#define NCOLS 256
#define NSEGS 512
#define NBLOCKS 2048
#define ROWS_PER_BLOCK (TOTAL_POINTS / NBLOCKS)  // 512

__global__ __launch_bounds__(256) void segsum_kernel(
    const float4* __restrict__ vals,   // (TOTAL_POINTS, 64) as float4
    const int* __restrict__ segids,    // (TOTAL_POINTS,)
    float* __restrict__ out)           // (NSEGS, 256), pre-zeroed
{
    const int c4 = threadIdx.x & 63;   // float4 column index 0..63 (lane id)
    const int rg = threadIdx.x >> 6;   // row group 0..3 (wave id)
    const long r0 = (long)blockIdx.x * ROWS_PER_BLOCK;

    float4 acc = make_float4(0.f, 0.f, 0.f, 0.f);
    int cur = -1;

    // Each wave streams rows r0+rg, r0+rg+4, ... — 1 KiB coalesced per row.
    // Segment id is wave-uniform (all 64 lanes read the same row's id).
    for (int i = rg; i < ROWS_PER_BLOCK; i += 4) {
        const long row = r0 + i;
        const int seg = segids[row];
        if (seg != cur) {
            if (cur >= 0) {
                float* o = out + (long)cur * NCOLS + c4 * 4;
                atomicAdd(o + 0, acc.x);
                atomicAdd(o + 1, acc.y);
                atomicAdd(o + 2, acc.z);
                atomicAdd(o + 3, acc.w);
            }
            cur = seg;
            acc = make_float4(0.f, 0.f, 0.f, 0.f);
        }
        const float4 v = vals[row * 64 + c4];
        acc.x += v.x; acc.y += v.y; acc.z += v.z; acc.w += v.w;
    }
    if (cur >= 0) {
        float* o = out + (long)cur * NCOLS + c4 * 4;
        atomicAdd(o + 0, acc.x);
        atomicAdd(o + 1, acc.y);
        atomicAdd(o + 2, acc.z);
        atomicAdd(o + 3, acc.w);
    }
}

extern "C" void kernel_launch(void* const* d_in, const int* in_sizes, int n_in,
                              void* d_out, int out_size, void* d_ws, size_t ws_size,
                              hipStream_t stream) {
    const float* vals = (const float*)d_in[0];
    const int* segids = (const int*)d_in[1];
    float* out = (float*)d_out;

    // Harness re-poisons d_out to 0xAA before every timed replay; zero it
    // ourselves (graph-capturable memset node). Also covers empty segments.
    hipMemsetAsync(out, 0, (size_t)out_size * sizeof(float), stream);

    segsum_kernel<<<NBLOCKS, 256, 0, stream>>>(
        (const float4*)vals, segids, out);
}

// Round 2
// 1316.249 us; speedup vs baseline: 1.0143x; 1.0143x over previous
//
#include <hip/hip_runtime.h>

// Segmented sum: values (1048576, 256) fp32, segment_ids sorted (1048576,) int32,
// out (512, 256) fp32. Memory-bound: 1.074 GB read -> ~176 us floor @ 6.3 TB/s.
//
// Sorted ids, avg run length ~2048 rows => ~78% of 512-row block chunks are
// single-segment (e^-0.25). Fast path: no per-row id loads, branch-free
// unrolled streaming sum, one atomic flush per wave. Slow path: run-tracking
// with atomic flush at each boundary.

#define TOTAL_POINTS 1048576
#define NCOLS 256
#define NSEGS 512
#define NBLOCKS 2048
#define ROWS_PER_BLOCK (TOTAL_POINTS / NBLOCKS)  // 512

typedef float v4 __attribute__((ext_vector_type(4)));

__global__ __launch_bounds__(256) void segsum_kernel(
    const v4* __restrict__ vals,       // (TOTAL_POINTS, 64) as float4
    const int* __restrict__ segids,    // (TOTAL_POINTS,)
    float* __restrict__ out)           // (NSEGS, 256), pre-zeroed
{
    const int c4 = threadIdx.x & 63;   // float4 column index 0..63 (lane id)
    const int rg = threadIdx.x >> 6;   // row group 0..3 (wave id)
    const long r0 = (long)blockIdx.x * ROWS_PER_BLOCK;

    const int segFirst = segids[r0];
    const int segLast  = segids[r0 + ROWS_PER_BLOCK - 1];

    v4 acc = (v4)(0.f);

    if (segFirst == segLast) {
        // ---- fast path: whole chunk is one segment (~78% of blocks) ----
        const v4* p = vals + (r0 + rg) * 64 + c4;
        #pragma unroll 8
        for (int i = 0; i < ROWS_PER_BLOCK / 4; ++i) {
            acc += __builtin_nontemporal_load(p);
            p += 4 * 64;               // stride 4 rows
        }
        float* o = out + (long)segFirst * NCOLS + c4 * 4;
        atomicAdd(o + 0, acc.x);
        atomicAdd(o + 1, acc.y);
        atomicAdd(o + 2, acc.z);
        atomicAdd(o + 3, acc.w);
        return;
    }

    // ---- slow path: chunk spans multiple segments ----
    int cur = -1;
    for (int i = rg; i < ROWS_PER_BLOCK; i += 4) {
        const long row = r0 + i;
        const int seg = segids[row];   // wave-uniform
        if (seg != cur) {
            if (cur >= 0) {
                float* o = out + (long)cur * NCOLS + c4 * 4;
                atomicAdd(o + 0, acc.x);
                atomicAdd(o + 1, acc.y);
                atomicAdd(o + 2, acc.z);
                atomicAdd(o + 3, acc.w);
            }
            cur = seg;
            acc = (v4)(0.f);
        }
        acc += __builtin_nontemporal_load(&vals[row * 64 + c4]);
    }
    if (cur >= 0) {
        float* o = out + (long)cur * NCOLS + c4 * 4;
        atomicAdd(o + 0, acc.x);
        atomicAdd(o + 1, acc.y);
        atomicAdd(o + 2, acc.z);
        atomicAdd(o + 3, acc.w);
    }
}

extern "C" void kernel_launch(void* const* d_in, const int* in_sizes, int n_in,
                              void* d_out, int out_size, void* d_ws, size_t ws_size,
                              hipStream_t stream) {
    const float* vals = (const float*)d_in[0];
    const int* segids = (const int*)d_in[1];
    float* out = (float*)d_out;

    // Harness re-poisons d_out to 0xAA before every timed replay; zero it
    // ourselves (graph-capturable memset node). Also covers empty segments.
    hipMemsetAsync(out, 0, (size_t)out_size * sizeof(float), stream);

    segsum_kernel<<<NBLOCKS, 256, 0, stream>>>(
        (const v4*)vals, segids, out);
}